// Round 4
// baseline (450.860 us; speedup 1.0000x reference)
//
#include <hip/hip_runtime.h>
#include <hip/hip_bf16.h>

#define ALPHA 0.2f

typedef __attribute__((ext_vector_type(8)))  __bf16 bf16x8;
typedef int          i32x4 __attribute__((ext_vector_type(4)));
typedef float        f32x4 __attribute__((ext_vector_type(4)));
typedef unsigned int u32x4 __attribute__((ext_vector_type(4)));

static __device__ __forceinline__ unsigned short bf16bits(float v) {
    __bf16 b = (__bf16)v;
    unsigned short u;
    __builtin_memcpy(&u, &b, 2);
    return u;
}

// ---------- Kernel 1: h = x*W ; f1 = h@a1 ; f2 = h@a2 ; hB = 16x16x32 B-fragment-packed h ----------
// hB layout: frag id = ks32*8 + ft16  (ks32 = j/32, ft16 = f/16), 512 bf16 per frag:
//   element(lane s, e) = h[j = ks32*32 + (s>>4)*8 + e][f = ft16*16 + (s&15)] at frag*512 + s*8 + e
__global__ __launch_bounds__(256) void gat_prep(
    const float* __restrict__ x, const float* __restrict__ W, const float* __restrict__ a,
    float* __restrict__ f1, float* __restrict__ f2, unsigned short* __restrict__ hB,
    float* __restrict__ ws_acc)
{
    __shared__ unsigned short lh[32][136];   // [j-local][f]
    int t = threadIdx.x;
    int i0 = blockIdx.x * 32;
    if (blockIdx.x == 0 && t < 128) ws_acc[t] = 0.0f;

    int row = t >> 3, q = t & 7;             // 8 threads per row, 16 f each
    int i = i0 + row;
    const float4* xp  = (const float4*)(x + (size_t)i * 128 + q * 16);
    const float4* wp  = (const float4*)(W + (size_t)i * 128 + q * 16);
    const float4* a1p = (const float4*)(a + q * 16);
    const float4* a2p = (const float4*)(a + 128 + q * 16);
    float p1 = 0.f, p2 = 0.f;
    #pragma unroll
    for (int jj = 0; jj < 4; ++jj) {
        float4 xv = xp[jj], wv = wp[jj], a1v = a1p[jj], a2v = a2p[jj];
        float h0 = xv.x * wv.x, h1 = xv.y * wv.y, h2 = xv.z * wv.z, h3 = xv.w * wv.w;
        p1 += h0 * a1v.x + h1 * a1v.y + h2 * a1v.z + h3 * a1v.w;
        p2 += h0 * a2v.x + h1 * a2v.y + h2 * a2v.z + h3 * a2v.w;
        int fb = q * 16 + jj * 4;
        lh[row][fb + 0] = bf16bits(h0);
        lh[row][fb + 1] = bf16bits(h1);
        lh[row][fb + 2] = bf16bits(h2);
        lh[row][fb + 3] = bf16bits(h3);
    }
    p1 += __shfl_xor(p1, 1); p1 += __shfl_xor(p1, 2); p1 += __shfl_xor(p1, 4);
    p2 += __shfl_xor(p2, 1); p2 += __shfl_xor(p2, 2); p2 += __shfl_xor(p2, 4);
    if (q == 0) { f1[i] = p1; f2[i] = p2; }
    __syncthreads();

    // fragment-pack: this block is exactly ks32 = blockIdx.x (32 j rows)
    int ftl = t >> 5, s0 = t & 31;
    size_t fragbase = ((size_t)blockIdx.x * 8 + ftl) * 512;
    #pragma unroll
    for (int hw = 0; hw < 2; ++hw) {
        int s = s0 + hw * 32;
        int jl = (s >> 4) * 8;
        int f = ftl * 16 + (s & 15);
        unsigned int p[4];
        #pragma unroll
        for (int k = 0; k < 4; ++k) {
            unsigned int lo = lh[jl + 2 * k][f];
            unsigned int hi = lh[jl + 2 * k + 1][f];
            p[k] = lo | (hi << 16);
        }
        u32x4 v = {p[0], p[1], p[2], p[3]};
        *(u32x4*)(hB + fragbase + s * 8) = v;
    }
}

// ---------- Kernel 2: producer/consumer fused attention + adj@W2 row sums ----------
// 512 blocks x 512 threads; block owns 16 rows; 16 chunks of 512 j.
// Waves 0-3 = producers (adj stream -> wg -> LDS ping-pong), waves 4-7 = consumers (MFMA chunk c-1).
__global__ __launch_bounds__(512, 4) void gat_main(
    const int* __restrict__ adj, const float* __restrict__ x,
    const float* __restrict__ W2, const float* __restrict__ f1g,
    const float* __restrict__ f2g, const unsigned short* __restrict__ hB,
    float* __restrict__ hp, float* __restrict__ ws_acc)
{
    __shared__ unsigned short wtile[2][16][536];   // 34.3 KB, stride 536 -> <=2-way banks
    __shared__ float den_s[16], rs_s[16];

    int tid = threadIdx.x;
    int wv = tid >> 6, l = tid & 63;
    int i0 = blockIdx.x * 16;
    bool producer = (wv < 4);
    int pw = wv & 3;
    int r0 = pw * 4;             // producer: 4 rows per wave
    int tf0 = (wv & 3) * 2;      // consumer: f-tiles 2cw, 2cw+1 (16 f each)

    float f1r[4] = {0.f, 0.f, 0.f, 0.f};
    float den4[4] = {0.f, 0.f, 0.f, 0.f}, rs4[4] = {0.f, 0.f, 0.f, 0.f};
    i32x4 adjreg[4][2];
    f32x4 f2reg[2], w2reg[2];
    const int* abase = adj;      // init'd properly for producers below
    f32x4 acc0 = {}, acc1 = {};

    if (producer) {
        #pragma unroll
        for (int ri = 0; ri < 4; ++ri) f1r[ri] = f1g[i0 + r0 + ri];
        abase = adj + (size_t)(i0 + r0) * 8192 + l * 4;
    }

    auto issue = [&](int c) {
        int j0 = c << 9;
        #pragma unroll
        for (int js = 0; js < 2; ++js) {
            int jo = j0 + js * 256 + l * 4;
            f2reg[js] = *(const f32x4*)(f2g + jo);
            w2reg[js] = *(const f32x4*)(W2 + jo);
            #pragma unroll
            for (int ri = 0; ri < 4; ++ri)
                adjreg[ri][js] = __builtin_nontemporal_load(
                    (const i32x4*)(abase + (size_t)ri * 8192 + j0 + js * 256));
        }
    };

    if (producer) issue(0);

    for (int c = 0; c <= 16; ++c) {
        if (producer) {
            if (c < 16) {
                int buf = c & 1;
                #pragma unroll
                for (int js = 0; js < 2; ++js) {
                    f32x4 f2v = f2reg[js], w2v = w2reg[js];
                    #pragma unroll
                    for (int ri = 0; ri < 4; ++ri) {
                        i32x4 ad = adjreg[ri][js];
                        float wg[4];
                        float dsum = 0.f, rsum = 0.f;
                        #pragma unroll
                        for (int e = 0; e < 4; ++e) {
                            float tt = f1r[ri] + f2v[e];
                            float lr = fmaxf(tt, ALPHA * tt);   // leakyrelu
                            float ex = __expf(lr);
                            float g = (ad[e] != 0) ? ex : 0.0f;
                            wg[e] = g;
                            dsum += g;
                            rsum += (ad[e] != 0) ? w2v[e] : 0.0f;
                        }
                        den4[ri] += dsum;
                        rs4[ri] += rsum;
                        unsigned int p0 = bf16bits(wg[0]) | ((unsigned int)bf16bits(wg[1]) << 16);
                        unsigned int p1 = bf16bits(wg[2]) | ((unsigned int)bf16bits(wg[3]) << 16);
                        *(uint2*)&wtile[buf][r0 + ri][js * 256 + l * 4] = make_uint2(p0, p1);
                    }
                }
                if (c < 15) issue(c + 1);
            } else {
                // c == 16: finalize den / rs while consumers drain chunk 15
                #pragma unroll
                for (int ri = 0; ri < 4; ++ri) {
                    float d = den4[ri], r = rs4[ri];
                    #pragma unroll
                    for (int off = 1; off < 64; off <<= 1) {
                        d += __shfl_xor(d, off);
                        r += __shfl_xor(r, off);
                    }
                    if (l == 0) { den_s[r0 + ri] = d; rs_s[r0 + ri] = r; }
                }
            }
        } else {
            if (c > 0) {
                int cc = c - 1;
                int buf = cc & 1;
                const unsigned short* ar = &wtile[buf][l & 15][(l >> 4) * 8];
                const unsigned short* bp = hB + (((size_t)cc * 16) * 8 + tf0) * 512 + l * 8;
                #pragma unroll
                for (int ks = 0; ks < 16; ++ks) {
                    bf16x8 af = *(const bf16x8*)(ar + ks * 32);
                    bf16x8 b0 = *(const bf16x8*)(bp + (size_t)ks * 4096);
                    bf16x8 b1 = *(const bf16x8*)(bp + (size_t)ks * 4096 + 512);
                    acc0 = __builtin_amdgcn_mfma_f32_16x16x32_bf16(af, b0, acc0, 0, 0, 0);
                    acc1 = __builtin_amdgcn_mfma_f32_16x16x32_bf16(af, b1, acc1, 0, 0, 0);
                }
            }
        }
        __syncthreads();
    }

    if (!producer) {
        // C/D: col = lane&15, row = (lane>>4)*4 + reg
        int col = l & 15, rq = l >> 4;
        #pragma unroll
        for (int reg = 0; reg < 4; ++reg) {
            int row = rq * 4 + reg;
            float dr = den_s[row];
            float inv = (dr != 0.f) ? 1.0f / dr : 0.f;
            __builtin_nontemporal_store(acc0[reg] * inv,
                hp + (size_t)(i0 + row) * 128 + tf0 * 16 + col);
            __builtin_nontemporal_store(acc1[reg] * inv,
                hp + (size_t)(i0 + row) * 128 + tf0 * 16 + 16 + col);
        }
    } else if (wv == 0) {
        // out-path partial: sum_i rs[i] * x[i][:] over this block's 16 rows
        float px = 0.f, py = 0.f;
        #pragma unroll 4
        for (int mm = 0; mm < 16; ++mm) {
            float rm = rs_s[mm];
            const float* xr = x + (size_t)(i0 + mm) * 128;
            px += rm * xr[l];
            py += rm * xr[l + 64];
        }
        atomicAdd(ws_acc + l, px);
        atomicAdd(ws_acc + l + 64, py);
    }
}

// ---------- Kernel 3: elu epilogue ----------
__global__ __launch_bounds__(128) void gat_finish(const float* __restrict__ ws_acc,
                                                  float* __restrict__ out)
{
    int t = threadIdx.x;
    float v = ws_acc[t];
    out[t] = (v > 0.f) ? v : (__expf(v) - 1.0f);
}

extern "C" void kernel_launch(void* const* d_in, const int* in_sizes, int n_in,
                              void* d_out, int out_size, void* d_ws, size_t ws_size,
                              hipStream_t stream) {
    const float* x   = (const float*)d_in[0];
    const int*   adj = (const int*)d_in[1];
    const float* W   = (const float*)d_in[2];
    const float* a   = (const float*)d_in[3];
    const float* W2  = (const float*)d_in[4];
    float* out = (float*)d_out;              // [0:128] elu out, [128:] h_prime [8192][128]

    float* wsf    = (float*)d_ws;
    float* ws_acc = wsf;                     // 128 floats
    float* f1     = wsf + 128;               // 8192 floats
    float* f2     = wsf + 128 + 8192;        // 8192 floats
    unsigned short* hB = (unsigned short*)(wsf + 128 + 2 * 8192);  // bf16, 2 MB fragment-packed

    gat_prep<<<256, 256, 0, stream>>>(x, W, a, f1, f2, hB, ws_acc);
    gat_main<<<512, 512, 0, stream>>>(adj, x, W2, f1, f2, hB, out + 128, ws_acc);
    gat_finish<<<1, 128, 0, stream>>>(ws_acc, out);
}